// Round 3
// baseline (57.486 us; speedup 1.0000x reference)
//
#include <hip/hip_runtime.h>
#include <math.h>

// Problem constants (B=8, H=W=64, P=60 frequencies, N=4096 grid points)
#define NBATCH 8
#define NP 60
#define NN 4096
#define MAGIC 0x5EC0FFEEu

// angle = 0.4*m radians for INTEGER m, |m| <= 3810.
// revolutions = m * (0.4/2pi); split the constant so the hi product is exact:
// Chi = 1043 * 2^-14 (11-bit mantissa; m*Chi exact for |m| < 4096),
// Clo = 0.4/(2pi) - Chi.  Hardware v_sin/v_cos take revolutions in [0,1).
__device__ __forceinline__ void sincos_m(float mf, float* s, float* c)
{
    const float Chi = 0.06365966796875f;
    const float Clo = 2.3092680081e-06f;
    float e = mf * Chi;                 // exact
    float f = e - floorf(e);            // exact fract of hi part
    float r = fmaf(mf, Clo, f);         // |mf*Clo| <= 0.0088
    r = r - floorf(r);
    *s = __builtin_amdgcn_sinf(r);
    *c = __builtin_amdgcn_cosf(r);
}

// ONE launch: 480 blocks = (b,p) pairs, 256 threads = 4 waves.
// Each block publishes (MAGIC<<32 | bits(partial)) to ws64[blk] with a
// device-scope atomicExch; block 0 spin-reads all slots with device-scope
// atomic loads (per-XCD L2s are not coherent -- plain loads would spin on a
// stale line) and produces the final scalar.  Correct for ANY initial d_ws
// contents: poison 0xAAAAAAAA != MAGIC, and values ride in the same word as
// the flag.
__global__ __launch_bounds__(256) void chf_fused(
    const float* __restrict__ dnn, const float* __restrict__ gt,
    unsigned long long* __restrict__ ws64, float* __restrict__ outp)
{
    __shared__ float Pre[256];
    __shared__ float Pim[256];
    __shared__ float Gre[64];
    __shared__ float Gim[64];
    __shared__ float Vals[NBATCH * NP];
    __shared__ float Sq[NBATCH];

    const int t    = threadIdx.x;
    const int blk  = blockIdx.x;
    const int b    = blk / NP;
    const int p    = blk - b * NP;
    const int lane = t & 63;
    const int g    = t >> 6;   // wave id 0..3

    // ---- Phase 1: G[w] = sum_h e^{i r_p y_h} * d[h][w] ----
    // lane = w (coalesced), wave g covers h in [16g,16g+16).
    // angle(h) = 0.4*(p-30)*(2h+1); base m=(p-30)(32g+1), step m=2(p-30).
    {
        const float fpm = (float)(p - 30);
        float c, s, cs, ss;
        sincos_m(fpm * (float)(32 * g + 1), &s, &c);
        sincos_m(fpm * 2.0f, &ss, &cs);
        float gr = 0.f, gi = 0.f;
        const float* ob = dnn + b * NN + g * 16 * 64 + lane;
        const float* gb = gt  + b * NN + g * 16 * 64 + lane;
        #pragma unroll
        for (int hh = 0; hh < 16; ++hh) {
            const float d = ob[hh * 64] - gb[hh * 64];
            gr = fmaf(c, d, gr);
            gi = fmaf(s, d, gi);
            const float cn = fmaf(c, cs, -(s * ss));
            const float sn = fmaf(s, cs,  (c * ss));
            c = cn; s = sn;
        }
        Pre[t] = gr;
        Pim[t] = gi;
    }
    __syncthreads();
    if (t < 64) {
        Gre[t] = Pre[t] + Pre[64 + t] + Pre[128 + t] + Pre[192 + t];
        Gim[t] = Pim[t] + Pim[64 + t] + Pim[128 + t] + Pim[192 + t];
    }
    __syncthreads();

    // ---- Phase 2: F[q] = sum_w e^{i r_q x_w} * G[w] ----
    // lane = q; wave g covers w in [16g,16g+16).
    {
        const float fqm = (float)(lane - 30);
        float c, s, cs, ss;
        sincos_m(fqm * (float)(32 * g + 1), &s, &c);
        sincos_m(fqm * 2.0f, &ss, &cs);
        float fr = 0.f, fi = 0.f;
        #pragma unroll
        for (int ww = 0; ww < 16; ++ww) {
            const int w = g * 16 + ww;
            const float xr = Gre[w];   // wave-broadcast
            const float xi = Gim[w];
            fr += c * xr - s * xi;
            fi += c * xi + s * xr;
            const float cn = fmaf(c, cs, -(s * ss));
            const float sn = fmaf(s, cs,  (c * ss));
            c = cn; s = sn;
        }
        Pre[t] = fr;
        Pim[t] = fi;
    }
    __syncthreads();

    // ---- Reduce sum_q |F[q]|^2 (lanes 60..63 are unused freqs, gated) ----
    if (t < 64) {
        const float Fr = Pre[t] + Pre[64 + t] + Pre[128 + t] + Pre[192 + t];
        const float Fi = Pim[t] + Pim[64 + t] + Pim[128 + t] + Pim[192 + t];
        float val = (t < NP) ? (Fr * Fr + Fi * Fi) : 0.f;
        #pragma unroll
        for (int off = 32; off > 0; off >>= 1)
            val += __shfl_down(val, off);
        if (t == 0)
            atomicExch(&ws64[blk], ((unsigned long long)MAGIC << 32) |
                                   (unsigned long long)__float_as_uint(val));
    }

    if (blk != 0) return;

    // ---- Block 0: gather all 480 partials, finish the loss ----
    for (int slot = t; slot < NBATCH * NP; slot += 256) {
        unsigned long long v;
        do {
            v = atomicAdd(&ws64[slot], 0ull);   // device-scope atomic load
        } while ((unsigned)(v >> 32) != MAGIC);
        Vals[slot] = __uint_as_float((unsigned)(v & 0xffffffffu));
    }
    __syncthreads();
    #pragma unroll
    for (int i = 0; i < 2; ++i) {
        const int bb = g * 2 + i;       // wave g handles batches 2g, 2g+1
        float v = (lane < NP) ? Vals[bb * NP + lane] : 0.f;
        #pragma unroll
        for (int off = 32; off > 0; off >>= 1)
            v += __shfl_down(v, off);
        if (lane == 0) Sq[bb] = sqrtf(v);
    }
    __syncthreads();
    if (t == 0) {
        float sum = 0.f;
        #pragma unroll
        for (int i = 0; i < NBATCH; ++i) sum += Sq[i];
        outp[0] = sum * 0.0125f;        // CHF_TIK / B = 0.1 / 8
    }
}

extern "C" void kernel_launch(void* const* d_in, const int* in_sizes, int n_in,
                              void* d_out, int out_size, void* d_ws, size_t ws_size,
                              hipStream_t stream)
{
    const float* dnn = (const float*)d_in[0];
    const float* gt  = (const float*)d_in[1];
    float* outp = (float*)d_out;
    unsigned long long* ws64 = (unsigned long long*)d_ws;  // 480 * 8 bytes

    chf_fused<<<NBATCH * NP, 256, 0, stream>>>(dnn, gt, ws64, outp);
}